// Round 8
// baseline (243.054 us; speedup 1.0000x reference)
//
#include <hip/hip_runtime.h>
#include <hip/hip_bf16.h>
#include <math.h>

#define T_DIM 1024
#define B_DIM 32
#define DIMF 512
#define DIMH 512
#define DIMS 1024
#define DIMW 512

typedef __attribute__((ext_vector_type(8))) short short8;
typedef __attribute__((ext_vector_type(4))) float f32x4;

__device__ __forceinline__ unsigned f2bf1(float x) {
    unsigned a = __float_as_uint(x);
    return (a + 0x7FFFu + ((a >> 16) & 1u)) >> 16;
}
__device__ __forceinline__ unsigned f2bf2(float lo, float hi) {
    return f2bf1(lo) | (f2bf1(hi) << 16);
}
__device__ __forceinline__ float fast_tanh(float x) {
    return 1.f - __fdividef(2.f, 1.f + __expf(x + x));
}
__device__ __forceinline__ unsigned short bf1(float x) {
    __hip_bfloat16 b = __float2bfloat16(x);
    return *reinterpret_cast<unsigned short*>(&b);
}
__device__ __forceinline__ short8 cvt_frag(const float* p) {
    const float4 a = *(const float4*)p;
    const float4 c = *(const float4*)(p + 4);
    union { unsigned short us[8]; short8 s; } u;
    u.us[0] = bf1(a.x); u.us[1] = bf1(a.y); u.us[2] = bf1(a.z); u.us[3] = bf1(a.w);
    u.us[4] = bf1(c.x); u.us[5] = bf1(c.y); u.us[6] = bf1(c.z); u.us[7] = bf1(c.w);
    return u.s;
}

// async global->LDS, 16B per lane; LDS dest wave-uniform (lane*16B implicit)
__device__ __forceinline__ void gl16(const unsigned short* g, unsigned short* l) {
    __builtin_amdgcn_global_load_lds(
        (const __attribute__((address_space(1))) unsigned int*)g,
        (__attribute__((address_space(3))) unsigned int*)l, 16, 0, 0);
}

// ---- GT[w][k ^ ((w&3)<<3)] = bf16((F@Uw)^T), chunk-swizzled; 8-row tiles ----
__global__ void k_G_gt(const float* __restrict__ F, const float* __restrict__ Uw,
                       unsigned short* __restrict__ GT) {
    __shared__ float Fs[8][DIMF];   // 16 KB
    const int r0 = blockIdx.x * 8;
    const int c  = blockIdx.y * 256 + threadIdx.x;
    const float4* Fv  = (const float4*)(F + (size_t)r0 * DIMF);
    float4* Fsv = (float4*)&Fs[0][0];
    for (int i = threadIdx.x; i < 8 * DIMF / 4; i += 256) Fsv[i] = Fv[i];
    __syncthreads();
    float acc[8];
#pragma unroll
    for (int r = 0; r < 8; ++r) acc[r] = 0.f;
    for (int k = 0; k < DIMF; ++k) {
        const float bv = Uw[(size_t)k * DIMW + c];
#pragma unroll
        for (int r = 0; r < 8; ++r) acc[r] = fmaf(Fs[r][k], bv, acc[r]);
    }
    uint4 o0;
    o0.x = f2bf2(acc[0], acc[1]); o0.y = f2bf2(acc[2], acc[3]);
    o0.z = f2bf2(acc[4], acc[5]); o0.w = f2bf2(acc[6], acc[7]);
    const int s3 = (c & 3) << 3;
    unsigned short* gout = GT + (size_t)c * T_DIM + (r0 & ~31);
    *(uint4*)(gout + ((r0 & 31) ^ s3)) = o0;
}

// ---- SWp[q][b][c] partial of s_prev@Ww (+Vb at q==0), grid (32,4) ----
__global__ void k_SW(const float* __restrict__ s_prev, const float* __restrict__ Ww,
                     const float* __restrict__ Vb, float* __restrict__ SWp) {
    __shared__ float ss[256];
    const int b = blockIdx.x, q = blockIdx.y;
    if (threadIdx.x < 64)
        ((float4*)ss)[threadIdx.x] =
            ((const float4*)(s_prev + (size_t)b * DIMS + q * 256))[threadIdx.x];
    __syncthreads();
    const int c0 = threadIdx.x, c1 = threadIdx.x + 256;
    float a0 = (q == 0) ? Vb[c0] : 0.f;
    float a1 = (q == 0) ? Vb[c1] : 0.f;
    const float* W = Ww + (size_t)q * 256 * DIMW;
    for (int k = 0; k < 256; ++k) {
        const float sv = ss[k];
        a0 = fmaf(sv, W[(size_t)k * DIMW + c0], a0);
        a1 = fmaf(sv, W[(size_t)k * DIMW + c1], a1);
    }
    SWp[((size_t)q * B_DIM + b) * DIMW + c0] = a0;
    SWp[((size_t)q * B_DIM + b) * DIMW + c1] = a1;
}

// ---- VwT[n][k ^ ((n&3)<<3)] = bf16(Vw[k][n]) chunk-swizzled ----
__global__ void k_pack_vwT(const float* __restrict__ Vw, unsigned short* __restrict__ VwT) {
    __shared__ float t[32][33];
    const int k0 = blockIdx.x * 32, n0 = blockIdx.y * 32;
    const int x = threadIdx.x & 31, y = threadIdx.x >> 5;
#pragma unroll
    for (int i = 0; i < 4; ++i)
        t[y + 8 * i][x] = Vw[(size_t)(k0 + y + 8 * i) * DIMW + n0 + x];
    __syncthreads();
#pragma unroll
    for (int i = 0; i < 4; ++i) {
        const int n = n0 + y + 8 * i;
        const int kk = (k0 + x) ^ ((n & 3) << 3);
        VwT[(size_t)n * DIMH + kk] = (unsigned short)f2bf1(t[x][y + 8 * i]);
    }
}

// ---- P[b][s][i] = bf16(a_logical[b][i+s]), 8 staggered copies ----
__global__ void k_pack_a(const float* __restrict__ a_prev, unsigned short* __restrict__ P) {
    const int bs = blockIdx.x;
    const int b = bs >> 3, s = bs & 7;
    for (int i = threadIdx.x; i < 2048; i += 256) {
        const int j = i + s;
        float v = 0.f;
        if (j >= 512 && j < 1536) v = a_prev[(size_t)b * T_DIM + j - 512];
        P[(size_t)bs * 2048 + i] = (unsigned short)f2bf1(v);
    }
}

// ---- hB[(b,t)][k] = bf16(h[t][b][k]), 16B stores ----
__global__ void k_pack_h(const float* __restrict__ h, unsigned short* __restrict__ hB) {
    for (unsigned i = blockIdx.x * 256 + threadIdx.x; i < 32768u * 64; i += gridDim.x * 256) {
        const int r = i >> 6, c8 = (i & 63) * 8;
        const int bb = r >> 10, t = r & 1023;
        const float* src = h + ((size_t)(t * 32 + bb)) * 512 + c8;
        const float4 v0 = *(const float4*)(src);
        const float4 v1 = *(const float4*)(src + 4);
        union { unsigned short us[8]; uint4 u4; } o;
        o.us[0] = (unsigned short)f2bf1(v0.x); o.us[1] = (unsigned short)f2bf1(v0.y);
        o.us[2] = (unsigned short)f2bf1(v0.z); o.us[3] = (unsigned short)f2bf1(v0.w);
        o.us[4] = (unsigned short)f2bf1(v1.x); o.us[5] = (unsigned short)f2bf1(v1.y);
        o.us[6] = (unsigned short)f2bf1(v1.z); o.us[7] = (unsigned short)f2bf1(v1.w);
        *(uint4*)(hB + (size_t)r * 512 + c8) = o.u4;
    }
}

// ---------------- main MFMA kernel: 8 waves, 64x32 wave-tile, ring-4, depth-3 B ----------------
// grid 1024 (XCD-swizzled), 512 threads, tile 128x128
template <bool PACKED>
__global__ void __launch_bounds__(512, 4) k_main(
    const float* __restrict__ hF, const unsigned short* __restrict__ hB,
    const unsigned short* __restrict__ VwT, const unsigned short* __restrict__ GT,
    const unsigned short* __restrict__ P, const float* __restrict__ SWp,
    const float* __restrict__ ww, float* __restrict__ ep) {
    __shared__ unsigned short Bs[4][128 * 32];   // 32 KB ring
    __shared__ float Ered[4][128];               // 2 KB epilogue reduce

    const int bid = blockIdx.x;
    const int wg  = (bid & 7) * 128 + (bid >> 3);   // bijective: 1024 % 8 == 0
    const int x = wg & 3, yy = wg >> 2;
    const int w0 = x * 128;
    const int b  = yy >> 3;
    const int t0 = (yy & 7) * 128;

    const int tid  = threadIdx.x;
    const int lane = tid & 63;
    const int wv   = tid >> 6;                      // 0..7
    const int wm = wv >> 2, wn = wv & 3;            // 2 x 4
    const int g = lane >> 4, r16 = lane & 15, g8 = g * 8;
    const int rowc = lane >> 2, kq = lane & 3;
    const int gx = g8 ^ ((r16 & 3) << 3);           // swizzled frag-read chunk

    f32x4 acc[4][2];
#pragma unroll
    for (int m = 0; m < 4; ++m)
#pragma unroll
        for (int n = 0; n < 2; ++n) acc[m][n] = (f32x4)0.f;

    // ---- A sources (per-lane register path); wave-tile rows: t0 + wm*64 .. +64 ----
    const int trow0 = t0 + wm * 64 + r16;
    const unsigned short* hA[4];
    const float* hAf[4];
#pragma unroll
    for (int m = 0; m < 4; ++m) {
        hA[m]  = hB + ((size_t)(b * 1024 + trow0 + m * 16)) * 512 + g8;
        hAf[m] = hF + ((size_t)(trow0 + m * 16) * B_DIM + b) * DIMH + g8;
    }
    const int kstart = max(0, t0 - 512);
    const int kend   = min(T_DIM - 1, t0 + 639);
    const int NS2    = (kend - kstart + 1) >> 5;    // even
    const int NT     = 16 + NS2;                    // even, 36..48
    const unsigned short* Pb = P + (size_t)b * 8 * 2048;
    const unsigned short* pA[4];
#pragma unroll
    for (int m = 0; m < 4; ++m) {
        const int trow = trow0 + m * 16;
        const int j0 = kstart + g8 + 1024 - trow;   // in [1, 2040]
        const int sj = j0 & 7;
        pA[m] = Pb + sj * 2048 + (j0 - sj);
    }
    const bool zrow = (trow0 == 0);

    // ---- B staging sources: wave wv stages rows wv*16..+16 (1 gl16, 1 KB) ----
    const int rB = wv * 16 + rowc;
    const unsigned short* vsrc = VwT + (size_t)(w0 + rB) * DIMH + kq * 8;
    const unsigned short* gsrc = GT  + (size_t)(w0 + rB) * T_DIM + kstart + kq * 8;

#define STAGEB(u2, j)                                                     \
    {                                                                     \
        if ((u2) < 16) gl16(vsrc + (u2) * 32, &Bs[j][wv * 512]);          \
        else           gl16(gsrc + ((u2) - 16) * 32, &Bs[j][wv * 512]);   \
    }
#define LOADA(AF, u1)                                                     \
    {                                                                     \
        if ((u1) < 16) {                                                  \
            if (PACKED) {                                                 \
                _Pragma("unroll")                                         \
                for (int m = 0; m < 4; ++m)                               \
                    AF[m] = *(const short8*)(hA[m] + (u1) * 32);          \
            } else {                                                      \
                _Pragma("unroll")                                         \
                for (int m = 0; m < 4; ++m)                               \
                    AF[m] = cvt_frag(hAf[m] + (u1) * 32);                 \
            }                                                             \
        } else {                                                          \
            _Pragma("unroll")                                             \
            for (int m = 0; m < 4; ++m)                                   \
                AF[m] = *(const short8*)(pA[m] + ((u1) - 16) * 32);       \
            if (zrow) AF[0] = (short8)(short)0;                           \
        }                                                                 \
    }
#define MFMA8(AF, BF)                                                     \
    {                                                                     \
        _Pragma("unroll")                                                 \
        for (int m = 0; m < 4; ++m)                                       \
            _Pragma("unroll")                                             \
            for (int n = 0; n < 2; ++n)                                   \
                acc[m][n] = __builtin_amdgcn_mfma_f32_16x16x32_bf16(      \
                    AF[m], BF[n], acc[m][n], 0, 0, 0);                    \
    }
// wait ladder: keep {g(u+2), g(u+3), A(u+1)} in flight; drain older
#define W6 { if (PACKED) asm volatile("s_waitcnt vmcnt(6)" ::: "memory");  \
             else        asm volatile("s_waitcnt vmcnt(10)" ::: "memory"); }
#define W5 { if (PACKED) asm volatile("s_waitcnt vmcnt(5)" ::: "memory");  \
             else        asm volatile("s_waitcnt vmcnt(9)" ::: "memory"); }
#define W4 { if (PACKED) asm volatile("s_waitcnt vmcnt(4)" ::: "memory");  \
             else        asm volatile("s_waitcnt vmcnt(8)" ::: "memory"); }
#define STEP(AFc, AFn, u)                                                 \
    {                                                                     \
        if ((u) + 1 < NT) LOADA(AFn, (u) + 1);                            \
        if ((u) + 3 < NT) STAGEB((u) + 3, (rc + 3) & 3);                  \
        short8 bf_[2];                                                    \
        _Pragma("unroll")                                                 \
        for (int n = 0; n < 2; ++n)                                       \
            bf_[n] = *(const short8*)(&Bs[rc][(wn * 32 + n * 16 + r16) * 32 + gx]); \
        asm volatile("s_waitcnt lgkmcnt(0)" ::: "memory");                \
        __builtin_amdgcn_sched_barrier(0);                                \
        MFMA8(AFc, bf_);                                                  \
        if ((u) + 3 < NT)      { W6; }                                    \
        else if ((u) + 2 < NT) { W5; }                                    \
        else if ((u) + 1 < NT) { W4; }                                    \
        else { asm volatile("s_waitcnt vmcnt(0)" ::: "memory"); }         \
        __builtin_amdgcn_s_barrier();                                     \
        rc = (rc + 1) & 3;                                                \
    }

    short8 afP[4], afQ[4];
    // ---- prologue: stage B(0..2); load A(0); wait B(0); barrier ----
    STAGEB(0, 0);
    STAGEB(1, 1);
    STAGEB(2, 2);
    LOADA(afP, 0);
    W6;
    __builtin_amdgcn_s_barrier();

    int rc = 0;
    for (int u = 0; u < NT; u += 2) {
        STEP(afP, afQ, u);
        STEP(afQ, afP, u + 1);
    }

#undef STAGEB
#undef LOADA
#undef MFMA8
#undef W6
#undef W5
#undef W4
#undef STEP

    // ---- epilogue: tanh, dot ww, r16-reduce, LDS wn-reduce, 4 partials ----
    float swv[2], wwv[2];
#pragma unroll
    for (int n = 0; n < 2; ++n) {
        const int w = w0 + wn * 32 + n * 16 + r16;
        float sv = 0.f;
#pragma unroll
        for (int q = 0; q < 4; ++q)
            sv += SWp[((size_t)q * B_DIM + b) * DIMW + w];
        swv[n] = sv;
        wwv[n] = ww[w];
    }
#pragma unroll
    for (int m = 0; m < 4; ++m) {
#pragma unroll
        for (int reg = 0; reg < 4; ++reg) {
            float s = 0.f;
#pragma unroll
            for (int n = 0; n < 2; ++n)
                s = fmaf(fast_tanh(acc[m][n][reg] + swv[n]), wwv[n], s);
            s += __shfl_xor(s, 1, 64);
            s += __shfl_xor(s, 2, 64);
            s += __shfl_xor(s, 4, 64);
            s += __shfl_xor(s, 8, 64);
            if (r16 == 0)
                Ered[wn][wm * 64 + m * 16 + g * 4 + reg] = s;
        }
    }
    __syncthreads();
    if (tid < 128) {
        const float v = Ered[0][tid] + Ered[1][tid] + Ered[2][tid] + Ered[3][tid];
        ep[((size_t)x * B_DIM + b) * T_DIM + t0 + tid] = v;
    }
}

// ---------------- softmax over t per batch (sums 4 e-partials) ----------------
__device__ __forceinline__ float decode_beta(const void* p) {
    const int iv = *(const int*)p;
    const float fv = __int_as_float(iv);
    const float afv = fabsf(fv);
    if (afv >= 1e-6f && afv <= 1e6f) return fv;
    return (float)iv;
}

__global__ void k_softmax(const float* __restrict__ ep, const void* __restrict__ beta_p,
                          float* __restrict__ out) {
    const int b = blockIdx.x;
    const float beta = decode_beta(beta_p);
    __shared__ float redm[4];
    __shared__ float reds[4];
    float v[4];
    float m = -INFINITY;
#pragma unroll
    for (int i = 0; i < 4; ++i) {
        const int t = threadIdx.x * 4 + i;
        float ev = 0.f;
#pragma unroll
        for (int xq = 0; xq < 4; ++xq)
            ev += ep[((size_t)xq * B_DIM + b) * T_DIM + t];
        v[i] = beta * ev;
        m = fmaxf(m, v[i]);
    }
    for (int off = 1; off < 64; off <<= 1) m = fmaxf(m, __shfl_xor(m, off, 64));
    const int wid = threadIdx.x >> 6, lane = threadIdx.x & 63;
    if (lane == 0) redm[wid] = m;
    __syncthreads();
    m = fmaxf(fmaxf(redm[0], redm[1]), fmaxf(redm[2], redm[3]));
    float s = 0.f;
    float ex[4];
#pragma unroll
    for (int i = 0; i < 4; ++i) { ex[i] = expf(v[i] - m); s += ex[i]; }
    for (int off = 1; off < 64; off <<= 1) s += __shfl_xor(s, off, 64);
    if (lane == 0) reds[wid] = s;
    __syncthreads();
    s = reds[0] + reds[1] + reds[2] + reds[3];
    const float inv = 1.f / s;
#pragma unroll
    for (int i = 0; i < 4; ++i)
        out[(size_t)b * T_DIM + threadIdx.x * 4 + i] = ex[i] * inv;
}

extern "C" void kernel_launch(void* const* d_in, const int* in_sizes, int n_in,
                              void* d_out, int out_size, void* d_ws, size_t ws_size,
                              hipStream_t stream) {
    const float* F      = (const float*)d_in[0];
    const float* a_prev = (const float*)d_in[1];
    const float* s_prev = (const float*)d_in[2];
    const float* h      = (const float*)d_in[3];
    const float* Ww     = (const float*)d_in[4];
    const float* Vw     = (const float*)d_in[5];
    const float* Vb     = (const float*)d_in[6];
    const float* Uw     = (const float*)d_in[7];
    const float* ww     = (const float*)d_in[8];
    const void*  beta_p = d_in[9];
    float* out = (float*)d_out;

    char* ws = (char*)d_ws;
    unsigned short* GT  = (unsigned short*)(ws);                        // 1 MB
    unsigned short* VwT = (unsigned short*)(ws + (1u << 20));           // 512 KB
    unsigned short* P   = (unsigned short*)(ws + (1u << 20) + (512u << 10));  // 1 MB
    float* SWp = (float*)(ws + (2u << 20) + (512u << 10));              // 256 KB
    float* ep  = (float*)(ws + (2u << 20) + (768u << 10));              // 512 KB (4 partials)
    unsigned short* hB = (unsigned short*)(ws + (4u << 20));            // 32 MB if available

    const bool big = ws_size >= (36ull << 20);

    k_G_gt    <<<dim3(128, 2), 256, 0, stream>>>(F, Uw, GT);
    k_pack_vwT<<<dim3(16, 16), 256, 0, stream>>>(Vw, VwT);
    k_pack_a  <<<dim3(256),    256, 0, stream>>>(a_prev, P);
    k_SW      <<<dim3(32, 4),  256, 0, stream>>>(s_prev, Ww, Vb, SWp);
    if (big) {
        k_pack_h<<<dim3(2048), 256, 0, stream>>>(h, hB);
        k_main<true><<<dim3(1024), 512, 0, stream>>>(h, hB, VwT, GT, P, SWp, ww, ep);
    } else {
        k_main<false><<<dim3(1024), 512, 0, stream>>>(h, hB, VwT, GT, P, SWp, ww, ep);
    }
    k_softmax <<<dim3(32),     256, 0, stream>>>(ep, beta_p, out);
}

// Round 9
// 145.858 us; speedup vs baseline: 1.6664x; 1.6664x over previous
//
#include <hip/hip_runtime.h>
#include <hip/hip_bf16.h>
#include <math.h>

#define T_DIM 1024
#define B_DIM 32
#define DIMF 512
#define DIMH 512
#define DIMS 1024
#define DIMW 512

typedef __attribute__((ext_vector_type(8))) short short8;
typedef __attribute__((ext_vector_type(4))) float f32x4;

__device__ __forceinline__ unsigned f2bf1(float x) {
    unsigned a = __float_as_uint(x);
    return (a + 0x7FFFu + ((a >> 16) & 1u)) >> 16;
}
__device__ __forceinline__ unsigned f2bf2(float lo, float hi) {
    return f2bf1(lo) | (f2bf1(hi) << 16);
}
__device__ __forceinline__ float fast_tanh(float x) {
    return 1.f - __fdividef(2.f, 1.f + __expf(x + x));
}
// pack 8 f32 (two float4) -> short8 bf16
__device__ __forceinline__ short8 pack8(float4 a, float4 c) {
    union { unsigned u[4]; short8 s; } o;
    o.u[0] = f2bf2(a.x, a.y); o.u[1] = f2bf2(a.z, a.w);
    o.u[2] = f2bf2(c.x, c.y); o.u[3] = f2bf2(c.z, c.w);
    return o.s;
}

// async global->LDS, 16B/lane; LDS dest wave-uniform, global src per-lane
__device__ __forceinline__ void gl16(const unsigned short* g, unsigned short* l) {
    __builtin_amdgcn_global_load_lds(
        (const __attribute__((address_space(1))) unsigned int*)g,
        (__attribute__((address_space(3))) unsigned int*)l, 16, 0, 0);
}
__device__ __forceinline__ void gl16f(const float* g, float* l) {
    __builtin_amdgcn_global_load_lds(
        (const __attribute__((address_space(1))) unsigned int*)g,
        (__attribute__((address_space(3))) unsigned int*)l, 16, 0, 0);
}

// ---- GT[w][k] = bf16((F@Uw)^T), linear (r2-verified) ----
__global__ void k_G_gt(const float* __restrict__ F, const float* __restrict__ Uw,
                       unsigned short* __restrict__ GT) {
    __shared__ float Fs[16][DIMF];
    const int r0 = blockIdx.x * 16;
    const int c  = blockIdx.y * 256 + threadIdx.x;
    const float4* Fv  = (const float4*)(F + (size_t)r0 * DIMF);
    float4* Fsv = (float4*)&Fs[0][0];
    for (int i = threadIdx.x; i < 16 * DIMF / 4; i += 256) Fsv[i] = Fv[i];
    __syncthreads();
    float acc[16];
#pragma unroll
    for (int r = 0; r < 16; ++r) acc[r] = 0.f;
    for (int k = 0; k < DIMF; ++k) {
        const float bv = Uw[(size_t)k * DIMW + c];
#pragma unroll
        for (int r = 0; r < 16; ++r) acc[r] = fmaf(Fs[r][k], bv, acc[r]);
    }
    uint4 o0, o1;
    o0.x = f2bf2(acc[0], acc[1]);   o0.y = f2bf2(acc[2], acc[3]);
    o0.z = f2bf2(acc[4], acc[5]);   o0.w = f2bf2(acc[6], acc[7]);
    o1.x = f2bf2(acc[8], acc[9]);   o1.y = f2bf2(acc[10], acc[11]);
    o1.z = f2bf2(acc[12], acc[13]); o1.w = f2bf2(acc[14], acc[15]);
    *(uint4*)(GT + (size_t)c * T_DIM + r0)     = o0;
    *(uint4*)(GT + (size_t)c * T_DIM + r0 + 8) = o1;
}

// ---- merged prep: [0,256) VwT pack, [256,512) P pack, [512,640) SW partials ----
__global__ void k_prep(const float* __restrict__ Vw, const float* __restrict__ a_prev,
                       const float* __restrict__ s_prev, const float* __restrict__ Ww,
                       const float* __restrict__ Vb, unsigned short* __restrict__ VwT,
                       unsigned short* __restrict__ P, float* __restrict__ SWp) {
    __shared__ float sh[1056];
    const int bz = blockIdx.x;
    if (bz < 256) {
        // VwT[n][k] = bf16(Vw[k][n]) linear
        const int k0 = (bz >> 4) * 32, n0 = (bz & 15) * 32;
        const int x = threadIdx.x & 31, y = threadIdx.x >> 5;
#pragma unroll
        for (int i = 0; i < 4; ++i)
            sh[(y + 8 * i) * 33 + x] = Vw[(size_t)(k0 + y + 8 * i) * DIMW + n0 + x];
        __syncthreads();
#pragma unroll
        for (int i = 0; i < 4; ++i) {
            const int n = n0 + y + 8 * i;
            VwT[(size_t)n * DIMH + k0 + x] = (unsigned short)f2bf1(sh[x * 33 + y + 8 * i]);
        }
    } else if (bz < 512) {
        // P[b][s][i] = bf16(a_logical[b][i+s])
        const int bs = bz - 256;
        const int b = bs >> 3, s = bs & 7;
        for (int i = threadIdx.x; i < 2048; i += 256) {
            const int j = i + s;
            float v = 0.f;
            if (j >= 512 && j < 1536) v = a_prev[(size_t)b * T_DIM + j - 512];
            P[(size_t)bs * 2048 + i] = (unsigned short)f2bf1(v);
        }
    } else {
        // SWp[q][b][c] partial of s_prev@Ww (+Vb at q==0)
        const int idx = bz - 512;
        const int b = idx & 31, q = idx >> 5;
        if (threadIdx.x < 64)
            ((float4*)sh)[threadIdx.x] =
                ((const float4*)(s_prev + (size_t)b * DIMS + q * 256))[threadIdx.x];
        __syncthreads();
        const int c0 = threadIdx.x, c1 = threadIdx.x + 256;
        float a0 = (q == 0) ? Vb[c0] : 0.f;
        float a1 = (q == 0) ? Vb[c1] : 0.f;
        const float* W = Ww + (size_t)q * 256 * DIMW;
        for (int k = 0; k < 256; ++k) {
            const float sv = sh[k];
            a0 = fmaf(sv, W[(size_t)k * DIMW + c0], a0);
            a1 = fmaf(sv, W[(size_t)k * DIMW + c1], a1);
        }
        SWp[((size_t)q * B_DIM + b) * DIMW + c0] = a0;
        SWp[((size_t)q * B_DIM + b) * DIMW + c1] = a1;
    }
}

// ---------------- main MFMA kernel: m97 structure, all-gl16 staging, no asm fences ----------------
// grid 1024 (XCD-swizzled), 256 threads (4 waves 2x2), tile 128x128, BK=32, single-buffered
__global__ void __launch_bounds__(256) k_main(
    const float* __restrict__ hF, const unsigned short* __restrict__ VwT,
    const unsigned short* __restrict__ GT, const unsigned short* __restrict__ P,
    const float* __restrict__ SWp, const float* __restrict__ ww,
    float* __restrict__ ep) {
    __shared__ __align__(16) char Araw[128 * 32 * 4];   // 16 KB: f32 A (part1) / bf16 A (part2)
    __shared__ unsigned short Bs[128 * 32];             // 8 KB
    float* AsF = (float*)Araw;
    unsigned short* As2 = (unsigned short*)Araw;

    const int bid = blockIdx.x;
    const int wg  = (bid & 7) * 128 + (bid >> 3);   // bijective: 1024 % 8 == 0
    const int x = wg & 3, yy = wg >> 2;
    const int w0 = x * 128;
    const int b  = yy >> 3;
    const int t0 = (yy & 7) * 128;

    const int tid  = threadIdx.x;
    const int lane = tid & 63;
    const int wv   = tid >> 6;
    const int wm = wv >> 1, wn = wv & 1;
    const int g = lane >> 4, r16 = lane & 15, g8 = g * 8;
    const int rowc = lane >> 2, kq = lane & 3;      // B staging: 16 rows x 4 chunks

    f32x4 acc[4][4];
#pragma unroll
    for (int m = 0; m < 4; ++m)
#pragma unroll
        for (int n = 0; n < 4; ++n) acc[m][n] = (f32x4)0.f;

    // ---- part1 A staging sources: f32 h, 8 rows/gl16, XOR chunk swizzle ----
    const int l8 = lane >> 3, l7 = lane & 7;        // row-in-8, chunk
    const float* aS[4];
#pragma unroll
    for (int q = 0; q < 4; ++q) {
        const int row = wv * 32 + q * 8 + l8;
        aS[q] = hF + ((size_t)(t0 + row) * B_DIM + b) * DIMH + ((l7 ^ l8) * 4);
    }
    // ---- B staging sources ----
    const int kstart = max(0, t0 - 512);
    const int kend   = min(T_DIM - 1, t0 + 639);
    const int NS2    = (kend - kstart + 1) >> 5;
    const unsigned short* vsrc = VwT + (size_t)(w0 + wv * 32 + rowc) * DIMH + kq * 8;
    const unsigned short* gsrc = GT  + (size_t)(w0 + wv * 32 + rowc) * T_DIM + kstart + kq * 8;
    // ---- part2 A staging sources: P staggered, constant per-lane pointer ----
    const unsigned short* Pb = P + (size_t)b * 8 * 2048;
    const int l4 = lane >> 2, l3 = lane & 3;
    const unsigned short* pS[2];
#pragma unroll
    for (int q = 0; q < 2; ++q) {
        const int row = wv * 32 + q * 16 + l4;
        const int jb = kstart + l3 * 8 + 1024 - (t0 + row);   // >= 385
        const int sj = jb & 7;
        pS[q] = Pb + sj * 2048 + (jb - sj);
    }
    const bool zrow = (t0 + wm * 64 + r16 == 0);

    // LDS staging dests (wave-uniform)
    unsigned short* Bd0 = &Bs[wv * 1024];
    unsigned short* Bd1 = &Bs[wv * 1024 + 512];
    // frag read constants
    const int s7 = r16 & 7;
    const int fc0 = ((2 * g) ^ s7) * 4, fc1 = ((2 * g + 1) ^ s7) * 4;

    // ================= part 1: h^T @ Vw, 16 steps =================
    for (int k0 = 0; k0 < DIMH; k0 += 32) {
        __syncthreads();   // previous compute's LDS reads done
#pragma unroll
        for (int q = 0; q < 4; ++q)
            gl16f(aS[q] + k0, AsF + (wv * 32 + q * 8) * 32);
        gl16(vsrc + k0, Bd0);
        gl16(vsrc + k0 + 16 * DIMH, Bd1);
        __syncthreads();   // staging visible (compiler drains vmcnt here)

        short8 af[4], bf[4];
#pragma unroll
        for (int m = 0; m < 4; ++m) {
            const int base = (wm * 64 + m * 16 + r16) * 32;
            const float4 lo = *(const float4*)&AsF[base + fc0];
            const float4 hi = *(const float4*)&AsF[base + fc1];
            af[m] = pack8(lo, hi);
        }
#pragma unroll
        for (int n = 0; n < 4; ++n)
            bf[n] = *(const short8*)&Bs[(wn * 64 + n * 16 + r16) * 32 + g8];
#pragma unroll
        for (int m = 0; m < 4; ++m)
#pragma unroll
            for (int n = 0; n < 4; ++n)
                acc[m][n] = __builtin_amdgcn_mfma_f32_16x16x32_bf16(af[m], bf[n], acc[m][n], 0, 0, 0);
    }

    // ================= part 2: Toeplitz(a) @ G, NS2 steps =================
    for (int s2 = 0; s2 < NS2; ++s2) {
        const int o = s2 * 32;
        __syncthreads();
        gl16(pS[0] + o, As2 + (wv * 32) * 32);
        gl16(pS[1] + o, As2 + (wv * 32 + 16) * 32);
        gl16(gsrc + o, Bd0);
        gl16(gsrc + o + 16 * T_DIM, Bd1);
        __syncthreads();

        short8 af[4], bf[4];
#pragma unroll
        for (int m = 0; m < 4; ++m)
            af[m] = *(const short8*)&As2[(wm * 64 + m * 16 + r16) * 32 + g8];
        if (zrow) af[0] = (short8)(short)0;   // f row t=0 is zero
#pragma unroll
        for (int n = 0; n < 4; ++n)
            bf[n] = *(const short8*)&Bs[(wn * 64 + n * 16 + r16) * 32 + g8];
#pragma unroll
        for (int m = 0; m < 4; ++m)
#pragma unroll
            for (int n = 0; n < 4; ++n)
                acc[m][n] = __builtin_amdgcn_mfma_f32_16x16x32_bf16(af[m], bf[n], acc[m][n], 0, 0, 0);
    }

    // ---- epilogue (r5-verified): tanh, dot ww, 16-lane reduce, per-(x,wn) partial ----
    float swv[4], wwv[4];
#pragma unroll
    for (int n = 0; n < 4; ++n) {
        const int w = w0 + wn * 64 + n * 16 + r16;
        float sv = 0.f;
#pragma unroll
        for (int q = 0; q < 4; ++q)
            sv += SWp[((size_t)q * B_DIM + b) * DIMW + w];
        swv[n] = sv;
        wwv[n] = ww[w];
    }
#pragma unroll
    for (int m = 0; m < 4; ++m) {
#pragma unroll
        for (int reg = 0; reg < 4; ++reg) {
            float s = 0.f;
#pragma unroll
            for (int n = 0; n < 4; ++n)
                s = fmaf(fast_tanh(acc[m][n][reg] + swv[n]), wwv[n], s);
            s += __shfl_xor(s, 1, 64);
            s += __shfl_xor(s, 2, 64);
            s += __shfl_xor(s, 4, 64);
            s += __shfl_xor(s, 8, 64);
            if (r16 == 0) {
                const int trow = t0 + wm * 64 + m * 16 + g * 4 + reg;
                ep[((size_t)(x * 2 + wn) * B_DIM + b) * T_DIM + trow] = s;
            }
        }
    }
}

// ---------------- softmax over t per batch (sums 8 e-partials, r5-verified) ----------------
__device__ __forceinline__ float decode_beta(const void* p) {
    const int iv = *(const int*)p;
    const float fv = __int_as_float(iv);
    const float afv = fabsf(fv);
    if (afv >= 1e-6f && afv <= 1e6f) return fv;
    return (float)iv;
}

__global__ void k_softmax(const float* __restrict__ ep, const void* __restrict__ beta_p,
                          float* __restrict__ out) {
    const int b = blockIdx.x;
    const float beta = decode_beta(beta_p);
    __shared__ float redm[4];
    __shared__ float reds[4];
    float v[4];
    float m = -INFINITY;
#pragma unroll
    for (int i = 0; i < 4; ++i) {
        const int t = threadIdx.x * 4 + i;
        float ev = 0.f;
#pragma unroll
        for (int xq = 0; xq < 8; ++xq)
            ev += ep[((size_t)xq * B_DIM + b) * T_DIM + t];
        v[i] = beta * ev;
        m = fmaxf(m, v[i]);
    }
    for (int off = 1; off < 64; off <<= 1) m = fmaxf(m, __shfl_xor(m, off, 64));
    const int wid = threadIdx.x >> 6, lane = threadIdx.x & 63;
    if (lane == 0) redm[wid] = m;
    __syncthreads();
    m = fmaxf(fmaxf(redm[0], redm[1]), fmaxf(redm[2], redm[3]));
    float s = 0.f;
    float ex[4];
#pragma unroll
    for (int i = 0; i < 4; ++i) { ex[i] = expf(v[i] - m); s += ex[i]; }
    for (int off = 1; off < 64; off <<= 1) s += __shfl_xor(s, off, 64);
    if (lane == 0) reds[wid] = s;
    __syncthreads();
    s = reds[0] + reds[1] + reds[2] + reds[3];
    const float inv = 1.f / s;
#pragma unroll
    for (int i = 0; i < 4; ++i)
        out[(size_t)b * T_DIM + threadIdx.x * 4 + i] = ex[i] * inv;
}

extern "C" void kernel_launch(void* const* d_in, const int* in_sizes, int n_in,
                              void* d_out, int out_size, void* d_ws, size_t ws_size,
                              hipStream_t stream) {
    const float* F      = (const float*)d_in[0];
    const float* a_prev = (const float*)d_in[1];
    const float* s_prev = (const float*)d_in[2];
    const float* h      = (const float*)d_in[3];
    const float* Ww     = (const float*)d_in[4];
    const float* Vw     = (const float*)d_in[5];
    const float* Vb     = (const float*)d_in[6];
    const float* Uw     = (const float*)d_in[7];
    const float* ww     = (const float*)d_in[8];
    const void*  beta_p = d_in[9];
    float* out = (float*)d_out;

    char* ws = (char*)d_ws;
    unsigned short* GT  = (unsigned short*)(ws);                              // 1 MB
    unsigned short* VwT = (unsigned short*)(ws + (1u << 20));                 // 512 KB
    unsigned short* P   = (unsigned short*)(ws + (1u << 20) + (512u << 10));  // 1 MB
    float* SWp = (float*)(ws + (2u << 20) + (512u << 10));                    // 256 KB
    float* ep  = (float*)(ws + (2u << 20) + (768u << 10));                    // 1 MB (8 partials)

    k_G_gt   <<<dim3(64, 2), 256, 0, stream>>>(F, Uw, GT);
    k_prep   <<<dim3(640),   256, 0, stream>>>(Vw, a_prev, s_prev, Ww, Vb, VwT, P, SWp);
    k_main   <<<dim3(1024),  256, 0, stream>>>(h, VwT, GT, P, SWp, ww, ep);
    k_softmax<<<dim3(32),    256, 0, stream>>>(ep, beta_p, out);
}

// Round 10
// 135.787 us; speedup vs baseline: 1.7900x; 1.0742x over previous
//
#include <hip/hip_runtime.h>
#include <hip/hip_bf16.h>
#include <math.h>

#define T_DIM 1024
#define B_DIM 32
#define DIMF 512
#define DIMH 512
#define DIMS 1024
#define DIMW 512

typedef __attribute__((ext_vector_type(8))) short short8;
typedef __attribute__((ext_vector_type(4))) float f32x4;

__device__ __forceinline__ unsigned f2bf1(float x) {
    unsigned a = __float_as_uint(x);
    return (a + 0x7FFFu + ((a >> 16) & 1u)) >> 16;
}
__device__ __forceinline__ unsigned f2bf2(float lo, float hi) {
    return f2bf1(lo) | (f2bf1(hi) << 16);
}
__device__ __forceinline__ float fast_tanh(float x) {
    return 1.f - __fdividef(2.f, 1.f + __expf(x + x));
}
__device__ __forceinline__ unsigned short bf1(float x) {
    __hip_bfloat16 b = __float2bfloat16(x);
    return *reinterpret_cast<unsigned short*>(&b);
}
// 8 f32 -> short8 bf16 (compiler emits v_cvt_pk_bf16_f32)
__device__ __forceinline__ short8 pack8(float4 a, float4 c) {
    union { unsigned short us[8]; short8 s; } u;
    u.us[0] = bf1(a.x); u.us[1] = bf1(a.y); u.us[2] = bf1(a.z); u.us[3] = bf1(a.w);
    u.us[4] = bf1(c.x); u.us[5] = bf1(c.y); u.us[6] = bf1(c.z); u.us[7] = bf1(c.w);
    return u.s;
}

// async global->LDS, 16B/lane; LDS dest wave-uniform, global src per-lane
__device__ __forceinline__ void gl16(const unsigned short* g, unsigned short* l) {
    __builtin_amdgcn_global_load_lds(
        (const __attribute__((address_space(1))) unsigned int*)g,
        (__attribute__((address_space(3))) unsigned int*)l, 16, 0, 0);
}
__device__ __forceinline__ void gl16f(const float* g, float* l) {
    __builtin_amdgcn_global_load_lds(
        (const __attribute__((address_space(1))) unsigned int*)g,
        (__attribute__((address_space(3))) unsigned int*)l, 16, 0, 0);
}

// ---- GT[w][k] = bf16((F@Uw)^T), linear ----
__global__ void k_G_gt(const float* __restrict__ F, const float* __restrict__ Uw,
                       unsigned short* __restrict__ GT) {
    __shared__ float Fs[16][DIMF];
    const int r0 = blockIdx.x * 16;
    const int c  = blockIdx.y * 256 + threadIdx.x;
    const float4* Fv  = (const float4*)(F + (size_t)r0 * DIMF);
    float4* Fsv = (float4*)&Fs[0][0];
    for (int i = threadIdx.x; i < 16 * DIMF / 4; i += 256) Fsv[i] = Fv[i];
    __syncthreads();
    float acc[16];
#pragma unroll
    for (int r = 0; r < 16; ++r) acc[r] = 0.f;
    for (int k = 0; k < DIMF; ++k) {
        const float bv = Uw[(size_t)k * DIMW + c];
#pragma unroll
        for (int r = 0; r < 16; ++r) acc[r] = fmaf(Fs[r][k], bv, acc[r]);
    }
    uint4 o0, o1;
    o0.x = f2bf2(acc[0], acc[1]);   o0.y = f2bf2(acc[2], acc[3]);
    o0.z = f2bf2(acc[4], acc[5]);   o0.w = f2bf2(acc[6], acc[7]);
    o1.x = f2bf2(acc[8], acc[9]);   o1.y = f2bf2(acc[10], acc[11]);
    o1.z = f2bf2(acc[12], acc[13]); o1.w = f2bf2(acc[14], acc[15]);
    *(uint4*)(GT + (size_t)c * T_DIM + r0)     = o0;
    *(uint4*)(GT + (size_t)c * T_DIM + r0 + 8) = o1;
}

// ---- merged prep: [0,256) VwT pack, [256,512) P pack, [512,640) SW partials ----
__global__ void k_prep(const float* __restrict__ Vw, const float* __restrict__ a_prev,
                       const float* __restrict__ s_prev, const float* __restrict__ Ww,
                       const float* __restrict__ Vb, unsigned short* __restrict__ VwT,
                       unsigned short* __restrict__ P, float* __restrict__ SWp) {
    __shared__ float sh[1056];
    const int bz = blockIdx.x;
    if (bz < 256) {
        const int k0 = (bz >> 4) * 32, n0 = (bz & 15) * 32;
        const int x = threadIdx.x & 31, y = threadIdx.x >> 5;
#pragma unroll
        for (int i = 0; i < 4; ++i)
            sh[(y + 8 * i) * 33 + x] = Vw[(size_t)(k0 + y + 8 * i) * DIMW + n0 + x];
        __syncthreads();
#pragma unroll
        for (int i = 0; i < 4; ++i) {
            const int n = n0 + y + 8 * i;
            VwT[(size_t)n * DIMH + k0 + x] = (unsigned short)f2bf1(sh[x * 33 + y + 8 * i]);
        }
    } else if (bz < 512) {
        const int bs = bz - 256;
        const int b = bs >> 3, s = bs & 7;
        for (int i = threadIdx.x; i < 2048; i += 256) {
            const int j = i + s;
            float v = 0.f;
            if (j >= 512 && j < 1536) v = a_prev[(size_t)b * T_DIM + j - 512];
            P[(size_t)bs * 2048 + i] = (unsigned short)f2bf1(v);
        }
    } else {
        const int idx = bz - 512;
        const int b = idx & 31, q = idx >> 5;
        if (threadIdx.x < 64)
            ((float4*)sh)[threadIdx.x] =
                ((const float4*)(s_prev + (size_t)b * DIMS + q * 256))[threadIdx.x];
        __syncthreads();
        const int c0 = threadIdx.x, c1 = threadIdx.x + 256;
        float a0 = (q == 0) ? Vb[c0] : 0.f;
        float a1 = (q == 0) ? Vb[c1] : 0.f;
        const float* W = Ww + (size_t)q * 256 * DIMW;
        for (int k = 0; k < 256; ++k) {
            const float sv = sh[k];
            a0 = fmaf(sv, W[(size_t)k * DIMW + c0], a0);
            a1 = fmaf(sv, W[(size_t)k * DIMW + c1], a1);
        }
        SWp[((size_t)q * B_DIM + b) * DIMW + c0] = a0;
        SWp[((size_t)q * B_DIM + b) * DIMW + c1] = a1;
    }
}

// ---------------- main MFMA kernel: BK=64, conflict-free swizzled LDS, all-gl16 ----------------
// grid 1024 (XCD-swizzled), 256 threads (4 waves 2x2), tile 128x128
__global__ void __launch_bounds__(256, 3) k_main(
    const float* __restrict__ hF, const unsigned short* __restrict__ VwT,
    const unsigned short* __restrict__ GT, const unsigned short* __restrict__ P,
    const float* __restrict__ SWp, const float* __restrict__ ww,
    float* __restrict__ ep) {
    __shared__ __align__(16) float AsF[128 * 64];       // 32 KB (part1 f32 A)
    __shared__ unsigned short Bs[128 * 64];             // 16 KB
    unsigned short* As2 = (unsigned short*)AsF;         // part2 bf16 A (16 KB alias)

    const int bid = blockIdx.x;
    const int wg  = (bid & 7) * 128 + (bid >> 3);   // bijective: 1024 % 8 == 0
    const int x = wg & 3, yy = wg >> 2;
    const int w0 = x * 128;
    const int b  = yy >> 3;
    const int t0 = (yy & 7) * 128;

    const int tid  = threadIdx.x;
    const int lane = tid & 63;
    const int wv   = tid >> 6;
    const int wm = wv >> 1, wn = wv & 1;
    const int g = lane >> 4, r16 = lane & 15;
    const int s7 = r16 & 7;

    f32x4 acc[4][4];
#pragma unroll
    for (int m = 0; m < 4; ++m)
#pragma unroll
        for (int n = 0; n < 4; ++n) acc[m][n] = (f32x4)0.f;

    const int kstart = max(0, t0 - 512);
    const int kend   = min(T_DIM - 1, t0 + 639);
    const int NS2    = (kend - kstart + 1) >> 6;    // 10..16 steps of K=64

    // ---- part1 A sources: 8 gl16/wave, 4 rows each (f32, pitch 256B) ----
    // LDS[row][c16] = h[row][c16 ^ (row&7)]  (c16 = 16B f32 chunk, 16/row)
    const float* hS[8];
    {
        const int rl = lane >> 4;                   // row-in-4
        const int cl = lane & 15;                   // 16B chunk
#pragma unroll
        for (int q = 0; q < 8; ++q) {
            const int row = wv * 32 + q * 4 + rl;
            hS[q] = hF + ((size_t)(t0 + row) * B_DIM + b) * DIMH + ((cl ^ (row & 7)) << 2);
        }
    }
    // ---- B sources: 4 gl16/wave, 8 rows each (bf16, pitch 128B) ----
    // LDS[row][c] = src[row][c ^ (row&7)]  (c = 16B chunk = 8 bf16, 8/row)
    const int rB = lane >> 3;                       // row-in-8 (= row&7)
    const int cB = ((lane & 7) ^ rB) * 8;           // src elem offset
    const unsigned short* vS[4];
    const unsigned short* gS[4];
#pragma unroll
    for (int q = 0; q < 4; ++q) {
        vS[q] = VwT + (size_t)(w0 + wv * 32 + q * 8 + rB) * DIMH + cB;
        gS[q] = GT  + (size_t)(w0 + wv * 32 + q * 8 + rB) * T_DIM + kstart + cB;
    }
    // ---- part2 A sources: P staggered, constant per-lane pointers ----
    const unsigned short* Pb = P + (size_t)b * 8 * 2048;
    const unsigned short* pS[4];
#pragma unroll
    for (int q = 0; q < 4; ++q) {
        const int row = wv * 32 + q * 8 + rB;
        const int jb = kstart + ((lane & 7) ^ rB) * 8 + 1024 - (t0 + row);  // in [385,1087]
        const int sj = jb & 7;
        pS[q] = Pb + sj * 2048 + (jb - sj);
    }
    const bool zrow = (t0 + wm * 64 + r16 == 0);

    // ================= part 1: h^T @ Vw, 8 steps of K=64 =================
    for (int k0 = 0; k0 < DIMH; k0 += 64) {
        __syncthreads();
#pragma unroll
        for (int q = 0; q < 8; ++q) gl16f(hS[q] + k0, AsF + (wv * 32 + q * 4) * 64);
#pragma unroll
        for (int q = 0; q < 4; ++q) gl16(vS[q] + k0, Bs + (wv * 32 + q * 8) * 64);
        __syncthreads();

#pragma unroll
        for (int ks = 0; ks < 2; ++ks) {
            short8 af[4], bf[4];
#pragma unroll
            for (int m = 0; m < 4; ++m) {
                const int base = (wm * 64 + m * 16 + r16) * 64;
                const int clo = ((ks * 8 + 2 * g) ^ s7) * 4;
                const int chi = ((ks * 8 + 2 * g + 1) ^ s7) * 4;
                af[m] = pack8(*(const float4*)&AsF[base + clo],
                              *(const float4*)&AsF[base + chi]);
            }
#pragma unroll
            for (int n = 0; n < 4; ++n)
                bf[n] = *(const short8*)&Bs[(wn * 64 + n * 16 + r16) * 64 +
                                            ((ks * 4 + g) ^ s7) * 8];
#pragma unroll
            for (int m = 0; m < 4; ++m)
#pragma unroll
                for (int n = 0; n < 4; ++n)
                    acc[m][n] = __builtin_amdgcn_mfma_f32_16x16x32_bf16(
                        af[m], bf[n], acc[m][n], 0, 0, 0);
        }
    }

    // ================= part 2: Toeplitz(a) @ G, NS2 steps of K=64 =================
    for (int s2 = 0; s2 < NS2; ++s2) {
        const int o = s2 * 64;
        __syncthreads();
#pragma unroll
        for (int q = 0; q < 4; ++q) gl16(pS[q] + o, As2 + (wv * 32 + q * 8) * 64);
#pragma unroll
        for (int q = 0; q < 4; ++q) gl16(gS[q] + o, Bs + (wv * 32 + q * 8) * 64);
        __syncthreads();

#pragma unroll
        for (int ks = 0; ks < 2; ++ks) {
            short8 af[4], bf[4];
#pragma unroll
            for (int m = 0; m < 4; ++m)
                af[m] = *(const short8*)&As2[(wm * 64 + m * 16 + r16) * 64 +
                                             ((ks * 4 + g) ^ s7) * 8];
            if (zrow) af[0] = (short8)(short)0;   // f row t=0 is zero
#pragma unroll
            for (int n = 0; n < 4; ++n)
                bf[n] = *(const short8*)&Bs[(wn * 64 + n * 16 + r16) * 64 +
                                            ((ks * 4 + g) ^ s7) * 8];
#pragma unroll
            for (int m = 0; m < 4; ++m)
#pragma unroll
                for (int n = 0; n < 4; ++n)
                    acc[m][n] = __builtin_amdgcn_mfma_f32_16x16x32_bf16(
                        af[m], bf[n], acc[m][n], 0, 0, 0);
        }
    }

    // ---- epilogue (r9-verified): tanh, dot ww, 16-lane reduce, per-(x,wn) partial ----
    float swv[4], wwv[4];
#pragma unroll
    for (int n = 0; n < 4; ++n) {
        const int w = w0 + wn * 64 + n * 16 + r16;
        float sv = 0.f;
#pragma unroll
        for (int q = 0; q < 4; ++q)
            sv += SWp[((size_t)q * B_DIM + b) * DIMW + w];
        swv[n] = sv;
        wwv[n] = ww[w];
    }
#pragma unroll
    for (int m = 0; m < 4; ++m) {
#pragma unroll
        for (int reg = 0; reg < 4; ++reg) {
            float s = 0.f;
#pragma unroll
            for (int n = 0; n < 4; ++n)
                s = fmaf(fast_tanh(acc[m][n][reg] + swv[n]), wwv[n], s);
            s += __shfl_xor(s, 1, 64);
            s += __shfl_xor(s, 2, 64);
            s += __shfl_xor(s, 4, 64);
            s += __shfl_xor(s, 8, 64);
            if (r16 == 0) {
                const int trow = t0 + wm * 64 + m * 16 + g * 4 + reg;
                ep[((size_t)(x * 2 + wn) * B_DIM + b) * T_DIM + trow] = s;
            }
        }
    }
}

// ---------------- softmax over t per batch (sums 8 e-partials, r9-verified) ----------------
__device__ __forceinline__ float decode_beta(const void* p) {
    const int iv = *(const int*)p;
    const float fv = __int_as_float(iv);
    const float afv = fabsf(fv);
    if (afv >= 1e-6f && afv <= 1e6f) return fv;
    return (float)iv;
}

__global__ void k_softmax(const float* __restrict__ ep, const void* __restrict__ beta_p,
                          float* __restrict__ out) {
    const int b = blockIdx.x;
    const float beta = decode_beta(beta_p);
    __shared__ float redm[4];
    __shared__ float reds[4];
    float v[4];
    float m = -INFINITY;
#pragma unroll
    for (int i = 0; i < 4; ++i) {
        const int t = threadIdx.x * 4 + i;
        float ev = 0.f;
#pragma unroll
        for (int xq = 0; xq < 8; ++xq)
            ev += ep[((size_t)xq * B_DIM + b) * T_DIM + t];
        v[i] = beta * ev;
        m = fmaxf(m, v[i]);
    }
    for (int off = 1; off < 64; off <<= 1) m = fmaxf(m, __shfl_xor(m, off, 64));
    const int wid = threadIdx.x >> 6, lane = threadIdx.x & 63;
    if (lane == 0) redm[wid] = m;
    __syncthreads();
    m = fmaxf(fmaxf(redm[0], redm[1]), fmaxf(redm[2], redm[3]));
    float s = 0.f;
    float ex[4];
#pragma unroll
    for (int i = 0; i < 4; ++i) { ex[i] = expf(v[i] - m); s += ex[i]; }
    for (int off = 1; off < 64; off <<= 1) s += __shfl_xor(s, off, 64);
    if (lane == 0) reds[wid] = s;
    __syncthreads();
    s = reds[0] + reds[1] + reds[2] + reds[3];
    const float inv = 1.f / s;
#pragma unroll
    for (int i = 0; i < 4; ++i)
        out[(size_t)b * T_DIM + threadIdx.x * 4 + i] = ex[i] * inv;
}

extern "C" void kernel_launch(void* const* d_in, const int* in_sizes, int n_in,
                              void* d_out, int out_size, void* d_ws, size_t ws_size,
                              hipStream_t stream) {
    const float* F      = (const float*)d_in[0];
    const float* a_prev = (const float*)d_in[1];
    const float* s_prev = (const float*)d_in[2];
    const float* h      = (const float*)d_in[3];
    const float* Ww     = (const float*)d_in[4];
    const float* Vw     = (const float*)d_in[5];
    const float* Vb     = (const float*)d_in[6];
    const float* Uw     = (const float*)d_in[7];
    const float* ww     = (const float*)d_in[8];
    const void*  beta_p = d_in[9];
    float* out = (float*)d_out;

    char* ws = (char*)d_ws;
    unsigned short* GT  = (unsigned short*)(ws);                              // 1 MB
    unsigned short* VwT = (unsigned short*)(ws + (1u << 20));                 // 512 KB
    unsigned short* P   = (unsigned short*)(ws + (1u << 20) + (512u << 10));  // 1 MB
    float* SWp = (float*)(ws + (2u << 20) + (512u << 10));                    // 256 KB
    float* ep  = (float*)(ws + (2u << 20) + (768u << 10));                    // 1 MB (8 partials)

    k_G_gt   <<<dim3(64, 2), 256, 0, stream>>>(F, Uw, GT);
    k_prep   <<<dim3(640),   256, 0, stream>>>(Vw, a_prev, s_prev, Ww, Vb, VwT, P, SWp);
    k_main   <<<dim3(1024),  256, 0, stream>>>(h, VwT, GT, P, SWp, ww, ep);
    k_softmax<<<dim3(32),    256, 0, stream>>>(ep, beta_p, out);
}